// Round 20
// baseline (174.955 us; speedup 1.0000x reference)
//
#include <hip/hip_runtime.h>
#include <hip/hip_bf16.h>
#include <math.h>

#define N_NODES 50000
#define N_EDGES 400000
#define HEADS   4
#define HC      512
#define IN_DIM  5
#define M_SEL   25000
#define NEG_SLOPE 0.2f

typedef __attribute__((ext_vector_type(8))) short bf16x8;
typedef __attribute__((ext_vector_type(4))) float f32x4;

__device__ inline unsigned short f2bf(float f) {
    union { float f; unsigned u; } v; v.f = f;
    unsigned r = v.u + 0x7FFF + ((v.u >> 16) & 1);   // RNE
    return (unsigned short)(r >> 16);
}
__device__ inline float bf2f(unsigned short b) {
    union { unsigned u; float f; } v; v.u = ((unsigned)b) << 16;
    return v.f;
}

// async 16B global->LDS (R14: took gemm 48->~26us)
#define GLOAD_LDS16(g, l)                                                  \
    __builtin_amdgcn_global_load_lds(                                      \
        (const __attribute__((address_space(1))) unsigned int*)(g),        \
        (__attribute__((address_space(3))) unsigned int*)(l), 16, 0, 0)

// ---------------------------------------------------------------------------
// k_init: W1/W2 fp32->bf16 cvt + part zero + deg=1 + done zero, one dispatch.
// ---------------------------------------------------------------------------
__global__ void k_init(const float* __restrict__ W1, const float* __restrict__ W2,
                       unsigned short* __restrict__ W1b, unsigned short* __restrict__ W2b,
                       float* __restrict__ part, int* __restrict__ deg,
                       int* __restrict__ done) {
    int i = blockIdx.x * 256 + threadIdx.x;   // grid 512*256 = 131072
    const float* src = (i < 65536) ? W1 : W2;
    unsigned short* dst = (i < 65536) ? W1b : W2b;
    int j = i & 65535;
    float4 v = ((const float4*)src)[j];
    ushort4 o;
    o.x = f2bf(v.x); o.y = f2bf(v.y); o.z = f2bf(v.z); o.w = f2bf(v.w);
    ((ushort4*)dst)[j] = o;
    if (i < 2 * M_SEL) part[i] = 0.f;
    if (i < N_NODES) deg[i] = 1;              // self-loop base for histogram
    if (i < 128) done[i] = 0;                 // gemm<1> panel counters
}

// ---------------------------------------------------------------------------
// Fused transform + hist. Blocks 0..1562: h = x@W.T (bf16) + a_src/a_dst.
// Blocks 1563..3125: degree histogram (deg pre-initialized by k_init).
// ---------------------------------------------------------------------------
#define TR_NPW 8
#define TR_BLKS 1563

__global__ __launch_bounds__(256) void k_transform_hist(
        const float* __restrict__ x, const float* __restrict__ W,
        const float* __restrict__ att_src, const float* __restrict__ att_dst,
        unsigned short* __restrict__ h, float* __restrict__ a_src,
        float* __restrict__ a_dst, const int* __restrict__ ei,
        int* __restrict__ deg) {
    if (blockIdx.x >= TR_BLKS) {
        int e = (blockIdx.x - TR_BLKS) * 256 + threadIdx.x;
        if (e < N_EDGES) atomicAdd(&deg[ei[N_EDGES + e]], 1);
        return;
    }
    int wave = threadIdx.x >> 6, lane = threadIdx.x & 63;
    int c0 = lane * 8;

    float wreg[40];
    const float4* wp = (const float4*)(W + c0 * IN_DIM);
#pragma unroll
    for (int i = 0; i < 10; i++) ((float4*)wreg)[i] = wp[i];
    float sas[8], sad[8];
    *(float4*)&sas[0] = *(const float4*)(att_src + c0);
    *(float4*)&sas[4] = *(const float4*)(att_src + c0 + 4);
    *(float4*)&sad[0] = *(const float4*)(att_dst + c0);
    *(float4*)&sad[4] = *(const float4*)(att_dst + c0 + 4);

    int n0 = (blockIdx.x * 4 + wave) * TR_NPW;
#pragma unroll
    for (int t = 0; t < TR_NPW; t++) {
        int n = n0 + t;
        if (n >= N_NODES) return;
        float xv[IN_DIM];
#pragma unroll
        for (int i = 0; i < IN_DIM; i++) xv[i] = x[n * IN_DIM + i];

        float ps = 0.f, pd = 0.f;
        bf16x8 hv8;
#pragma unroll
        for (int j = 0; j < 8; j++) {
            float acc = 0.f;
#pragma unroll
            for (int i = 0; i < IN_DIM; i++) acc += xv[i] * wreg[j * IN_DIM + i];
            hv8[j] = (short)f2bf(acc);
            ps += acc * sas[j];
            pd += acc * sad[j];
        }
        *(bf16x8*)(h + (size_t)n * HC + c0) = hv8;

#pragma unroll
        for (int off = 8; off >= 1; off >>= 1) {
            ps += __shfl_xor(ps, off);
            pd += __shfl_xor(pd, off);
        }
        if ((lane & 15) == 0) {
            int head = lane >> 4;
            a_src[n * HEADS + head] = ps;
            a_dst[n * HEADS + head] = pd;
        }
    }
}

// ---------------------------------------------------------------------------
// CSR build (multi-block; R4 lesson: never single-block the scan)
// ---------------------------------------------------------------------------
#define NSCAN_BLK 196

__global__ void k_scan1(const int* __restrict__ deg, int* __restrict__ excl,
                        int* __restrict__ bsum) {
    __shared__ int s[256];
    int i = blockIdx.x * 256 + threadIdx.x;
    int v = (i < N_NODES) ? deg[i] : 0;
    s[threadIdx.x] = v;
    __syncthreads();
    for (int off = 1; off < 256; off <<= 1) {
        int t = (threadIdx.x >= off) ? s[threadIdx.x - off] : 0;
        __syncthreads();
        s[threadIdx.x] += t;
        __syncthreads();
    }
    if (i < N_NODES) excl[i] = s[threadIdx.x] - v;
    if (threadIdx.x == 255) bsum[blockIdx.x] = s[255];
}

__global__ void k_scan3fill(const int* __restrict__ excl, const int* __restrict__ bsum,
                            int* __restrict__ offs, int* __restrict__ curs,
                            int* __restrict__ csr) {
    __shared__ int part[256];
    int tid = threadIdx.x;
    part[tid] = (tid < NSCAN_BLK) ? bsum[tid] : 0;
    __syncthreads();
    for (int off = 1; off < 256; off <<= 1) {
        int t = (tid >= off) ? part[tid - off] : 0;
        __syncthreads();
        part[tid] += t;
        __syncthreads();
    }
    int blockoff = (blockIdx.x == 0) ? 0 : part[blockIdx.x - 1];
    int i = blockIdx.x * 256 + tid;
    if (i < N_NODES) {
        int o = excl[i] + blockoff;
        offs[i] = o;
        csr[o] = i;          // self loop in slot 0
        curs[i] = o + 1;
    }
}

__global__ void k_fill_edges(const int* __restrict__ ei, int* __restrict__ cursor,
                             int* __restrict__ csr) {
    int e = blockIdx.x * 256 + threadIdx.x;
    if (e < N_EDGES) {
        int d = ei[N_EDGES + e];
        int pos = atomicAdd(&cursor[d], 1);
        csr[pos] = ei[e];
    }
}

// ---------------------------------------------------------------------------
// Aggregate — R5/R18 body, but 1024-thread blocks (16 waves/block).
// R19 counters: VGPR 28, zero LDS, yet occupancy 51% => limited by per-CU
// WORKGROUP SLOTS (4 waves x ~4 slots), not registers. 16 waves/block
// packs up to 32 waves/CU in 2 slots. Latency-bound => scales with TLP.
// ---------------------------------------------------------------------------
__global__ __launch_bounds__(1024) void k_aggregate(
        const unsigned short* __restrict__ h, const float* __restrict__ a_src,
        const float* __restrict__ a_dst, const int* __restrict__ csr,
        const int* __restrict__ offs, const int* __restrict__ deg,
        const float* __restrict__ bias, unsigned short* __restrict__ emb_sel) {
    int wave = threadIdx.x >> 6, lane = threadIdx.x & 63;
    int w = blockIdx.x * 16 + wave;
    if (w >= M_SEL) return;
    int n = ((w >> 2) << 3) + (w & 3);   // TEAM_IDX[w]

    int base = offs[n];
    int dn = deg[n];
    int head = lane >> 4, egrp = lane & 15;
    int c0 = lane * 8;

    float acc[8];
#pragma unroll
    for (int j = 0; j < 8; j++) acc[j] = -INFINITY;

    if (dn <= 16) {
        int s_e = 0;
        float t = -INFINITY;
        if (egrp < dn) {
            s_e = csr[base + egrp];
            t = a_src[s_e * HEADS + head] + a_dst[n * HEADS + head];
            t = (t > 0.f) ? t : NEG_SLOPE * t;
        }
        float m = t;
#pragma unroll
        for (int off = 8; off >= 1; off >>= 1) m = fmaxf(m, __shfl_xor(m, off));
        float ex = (egrp < dn) ? __expf(t - m) : 0.f;
        float den = ex;
#pragma unroll
        for (int off = 8; off >= 1; off >>= 1) den += __shfl_xor(den, off);
        float attn = ex / den;   // this lane's edge attn (for its head)

        int e = 0;
        for (; e + 4 <= dn; e += 4) {
            int s0 = __shfl(s_e, e + 0), s1 = __shfl(s_e, e + 1);
            int s2 = __shfl(s_e, e + 2), s3 = __shfl(s_e, e + 3);
            float a0 = __shfl(attn, (head << 4) | (e + 0));
            float a1 = __shfl(attn, (head << 4) | (e + 1));
            float a2 = __shfl(attn, (head << 4) | (e + 2));
            float a3 = __shfl(attn, (head << 4) | (e + 3));
            bf16x8 v0 = *(const bf16x8*)(h + (size_t)s0 * HC + c0);
            bf16x8 v1 = *(const bf16x8*)(h + (size_t)s1 * HC + c0);
            bf16x8 v2 = *(const bf16x8*)(h + (size_t)s2 * HC + c0);
            bf16x8 v3 = *(const bf16x8*)(h + (size_t)s3 * HC + c0);
#pragma unroll
            for (int j = 0; j < 8; j++) {
                acc[j] = fmaxf(acc[j], bf2f((unsigned short)v0[j]) * a0);
                acc[j] = fmaxf(acc[j], bf2f((unsigned short)v1[j]) * a1);
                acc[j] = fmaxf(acc[j], bf2f((unsigned short)v2[j]) * a2);
                acc[j] = fmaxf(acc[j], bf2f((unsigned short)v3[j]) * a3);
            }
        }
        for (; e < dn; e++) {
            int s = __shfl(s_e, e);
            float a = __shfl(attn, (head << 4) | e);
            bf16x8 v = *(const bf16x8*)(h + (size_t)s * HC + c0);
#pragma unroll
            for (int j = 0; j < 8; j++)
                acc[j] = fmaxf(acc[j], bf2f((unsigned short)v[j]) * a);
        }
    } else {
        // fallback: 3-pass (rare, dn>16)
        float adn = a_dst[n * HEADS + head];
        float m = -INFINITY;
        for (int e0 = 0; e0 < dn; e0 += 16) {
            int e = e0 + egrp;
            if (e < dn) {
                int s = csr[base + e];
                float t = a_src[s * HEADS + head] + adn;
                t = (t > 0.f) ? t : NEG_SLOPE * t;
                m = fmaxf(m, t);
            }
        }
#pragma unroll
        for (int off = 8; off >= 1; off >>= 1) m = fmaxf(m, __shfl_xor(m, off));
        float den = 0.f;
        for (int e0 = 0; e0 < dn; e0 += 16) {
            int e = e0 + egrp;
            if (e < dn) {
                int s = csr[base + e];
                float t = a_src[s * HEADS + head] + adn;
                t = (t > 0.f) ? t : NEG_SLOPE * t;
                den += __expf(t - m);
            }
        }
#pragma unroll
        for (int off = 8; off >= 1; off >>= 1) den += __shfl_xor(den, off);
        float invden = 1.0f / den;
        for (int e = 0; e < dn; e++) {
            int s = csr[base + e];
            float t = a_src[s * HEADS + head] + adn;
            t = (t > 0.f) ? t : NEG_SLOPE * t;
            float attn = __expf(t - m) * invden;
            bf16x8 hv = *(const bf16x8*)(h + (size_t)s * HC + c0);
#pragma unroll
            for (int j = 0; j < 8; j++)
                acc[j] = fmaxf(acc[j], bf2f((unsigned short)hv[j]) * attn);
        }
    }

    bf16x8 ov;
#pragma unroll
    for (int j = 0; j < 8; j++) ov[j] = (short)f2bf(acc[j] + bias[c0 + j]);
    *(bf16x8*)(emb_sel + (size_t)w * HC + c0) = ov;
}

// ---------------------------------------------------------------------------
// GEMM (R18 structure + XCD-affinity + fused tanh), unchanged from R19.
// ---------------------------------------------------------------------------
template <int MODE>
__global__ __launch_bounds__(256, 2) void k_gemm(const unsigned short* __restrict__ A, int M,
                                                 const unsigned short* __restrict__ Wt,
                                                 const float* __restrict__ bias,
                                                 unsigned short* __restrict__ C,
                                                 const float* __restrict__ W3,
                                                 float* __restrict__ part,
                                                 int* __restrict__ done,
                                                 const float* __restrict__ b3,
                                                 float* __restrict__ outp) {
    __shared__ unsigned short As[256 * 64];   // 32KB
    __shared__ unsigned short Bs[128 * 64];   // 16KB
    int tid = threadIdx.x;
    int bid = blockIdx.x;
    int xcd = bid & 7, q = bid >> 3;
    int p = xcd + 8 * (q >> 2);               // m-panel 0..97 (+ holes)
    int xb = q & 3;                           // n-block 0..3
    if (p >= 98) return;
    int m0 = p * 256;
    int o0 = xb * 128;
    int wv = tid >> 6, lane = tid & 63;       // wave = m-stripe

    f32x4 acc[4][8];
#pragma unroll
    for (int i = 0; i < 4; i++)
#pragma unroll
        for (int j = 0; j < 8; j++) acc[i][j] = (f32x4){0.f, 0.f, 0.f, 0.f};

    for (int k0 = 0; k0 < HC; k0 += 64) {
#pragma unroll
        for (int c = 0; c < 8; c++) {         // A: 256x64 = 32KB
            int off = c * 4096 + tid * 16;
            int row = off >> 7, col = (off & 127) >> 1;
            GLOAD_LDS16(A + (size_t)(m0 + row) * HC + k0 + col, (char*)As + off);
        }
#pragma unroll
        for (int c = 0; c < 4; c++) {         // B: 128x64 = 16KB
            int off = c * 4096 + tid * 16;
            int row = off >> 7, col = (off & 127) >> 1;
            GLOAD_LDS16(Wt + (size_t)(o0 + row) * HC + k0 + col, (char*)Bs + off);
        }
        __syncthreads();   // drains vmcnt: staged data visible

#pragma unroll
        for (int kk = 0; kk < 2; kk++) {
            int kb = kk * 32 + (lane >> 4) * 8;
            bf16x8 af[4], bfr[8];
#pragma unroll
            for (int mi = 0; mi < 4; mi++)
                af[mi] = *(const bf16x8*)(&As[(wv * 64 + mi * 16 + (lane & 15)) * 64 + kb]);
#pragma unroll
            for (int ni = 0; ni < 8; ni++)
                bfr[ni] = *(const bf16x8*)(&Bs[(ni * 16 + (lane & 15)) * 64 + kb]);
#pragma unroll
            for (int mi = 0; mi < 4; mi++)
#pragma unroll
                for (int ni = 0; ni < 8; ni++)
                    acc[mi][ni] = __builtin_amdgcn_mfma_f32_16x16x32_bf16(
                        af[mi], bfr[ni], acc[mi][ni], 0, 0, 0);
        }
        __syncthreads();   // before next stage overwrites the buffer
    }

    if (MODE == 0) {
#pragma unroll
        for (int ni = 0; ni < 8; ni++) {
            int ncol = o0 + ni * 16 + (lane & 15);
            float bv = bias[ncol];
#pragma unroll
            for (int mi = 0; mi < 4; mi++) {
                int mbase = m0 + wv * 64 + mi * 16 + (lane >> 4) * 4;
#pragma unroll
                for (int r = 0; r < 4; r++) {
                    int m = mbase + r;
                    if (m < M) {
                        float v = fmaxf(acc[mi][ni][r] + bv, 0.f);
                        C[(size_t)m * HC + ncol] = f2bf(v);
                    }
                }
            }
        }
    } else {
        float p0[4][4], p1[4][4];
#pragma unroll
        for (int mi = 0; mi < 4; mi++)
#pragma unroll
            for (int r = 0; r < 4; r++) { p0[mi][r] = 0.f; p1[mi][r] = 0.f; }
#pragma unroll
        for (int ni = 0; ni < 8; ni++) {
            int ncol = o0 + ni * 16 + (lane & 15);
            float bv = bias[ncol];
            float w0 = W3[ncol], w1 = W3[HC + ncol];
#pragma unroll
            for (int mi = 0; mi < 4; mi++)
#pragma unroll
                for (int r = 0; r < 4; r++) {
                    float v = fmaxf(acc[mi][ni][r] + bv, 0.f);
                    p0[mi][r] += v * w0;
                    p1[mi][r] += v * w1;
                }
        }
#pragma unroll
        for (int mi = 0; mi < 4; mi++)
#pragma unroll
            for (int r = 0; r < 4; r++) {
                float a0 = p0[mi][r], a1 = p1[mi][r];
#pragma unroll
                for (int off = 8; off >= 1; off >>= 1) {
                    a0 += __shfl_xor(a0, off);
                    a1 += __shfl_xor(a1, off);
                }
                int m = m0 + wv * 64 + mi * 16 + (lane >> 4) * 4 + r;
                if ((lane & 15) == 0 && m < M) {
                    atomicAdd(&part[m * 2 + 0], a0);
                    atomicAdd(&part[m * 2 + 1], a1);
                }
            }

        // completion: last of the panel's 4 blocks applies tanh (fused k_tanh)
        __syncthreads();
        __shared__ int lastf;
        if (tid == 0) {
            __threadfence();
            int old = atomicAdd(&done[p], 1);
            lastf = (old == 3);
        }
        __syncthreads();
        if (lastf) {
            for (int i = tid; i < 512; i += 256) {
                int idx = p * 512 + i;
                if (idx < 2 * M_SEL) {
                    float v = __hip_atomic_load(&part[idx], __ATOMIC_RELAXED,
                                                __HIP_MEMORY_SCOPE_AGENT);
                    outp[idx] = tanhf(v + b3[i & 1]);
                }
            }
        }
    }
}

// ---------------------------------------------------------------------------
extern "C" void kernel_launch(void* const* d_in, const int* in_sizes, int n_in,
                              void* d_out, int out_size, void* d_ws, size_t ws_size,
                              hipStream_t stream) {
    const float* x       = (const float*)d_in[0];
    const int*   ei      = (const int*)d_in[1];
    const float* W       = (const float*)d_in[3];
    const float* att_src = (const float*)d_in[4];
    const float* att_dst = (const float*)d_in[5];
    const float* bias    = (const float*)d_in[6];
    const float* W1      = (const float*)d_in[7];
    const float* b1      = (const float*)d_in[8];
    const float* W2      = (const float*)d_in[9];
    const float* b2      = (const float*)d_in[10];
    const float* W3      = (const float*)d_in[11];
    const float* b3      = (const float*)d_in[12];
    float* out = (float*)d_out;

    char* ws = (char*)d_ws;
    unsigned short* h       = (unsigned short*)(ws);               // 51,200,000
    unsigned short* emb_sel = (unsigned short*)(ws + 51200000);    // 25,600,000
    unsigned short* h1      = (unsigned short*)(ws + 76800000);    // 25,600,000
    float* part  = (float*)(ws + 102400000);                       //    200,000 (also OOB-read slack)
    float* a_src = (float*)(ws + 102600000);                       //    800,000
    float* a_dst = (float*)(ws + 103400000);                       //    800,000
    int*   deg   = (int*)  (ws + 104200000);                       //    200,000
    int*   offs  = (int*)  (ws + 104400000);                       //    200,000
    int*   curs  = (int*)  (ws + 104600000);                       //    200,000
    int*   excl  = (int*)  (ws + 104800000);                       //    200,000
    int*   bsum  = (int*)  (ws + 105000000);                       //      1,024
    int*   done  = (int*)  (ws + 105001024);                       //        512
    int*   csr   = (int*)  (ws + 105001536);                       //  1,800,000
    unsigned short* W1b = (unsigned short*)(ws + 106801536);       //    524,288
    unsigned short* W2b = (unsigned short*)(ws + 107325824);       //    524,288  (~108 MB)

    k_init<<<512, 256, 0, stream>>>(W1, W2, W1b, W2b, part, deg, done);
    k_transform_hist<<<TR_BLKS * 2, 256, 0, stream>>>(x, W, att_src, att_dst, h,
                                                      a_src, a_dst, ei, deg);
    k_scan1<<<NSCAN_BLK, 256, 0, stream>>>(deg, excl, bsum);
    k_scan3fill<<<NSCAN_BLK, 256, 0, stream>>>(excl, bsum, offs, curs, csr);
    k_fill_edges<<<(N_EDGES + 255) / 256, 256, 0, stream>>>(ei, curs, csr);
    k_aggregate<<<(M_SEL + 15) / 16, 1024, 0, stream>>>(h, a_src, a_dst, csr, offs,
                                                        deg, bias, emb_sel);

    k_gemm<0><<<416, 256, 0, stream>>>(emb_sel, M_SEL, W1b, b1, h1, nullptr, nullptr,
                                       nullptr, nullptr, nullptr);
    k_gemm<1><<<416, 256, 0, stream>>>(h1, M_SEL, W2b, b2, nullptr, W3, part,
                                       done, b3, out);
}

// Round 21
// 174.337 us; speedup vs baseline: 1.0035x; 1.0035x over previous
//
#include <hip/hip_runtime.h>
#include <hip/hip_bf16.h>
#include <math.h>

#define N_NODES 50000
#define N_EDGES 400000
#define HEADS   4
#define HC      512
#define IN_DIM  5
#define M_SEL   25000
#define NEG_SLOPE 0.2f

typedef __attribute__((ext_vector_type(8))) short bf16x8;
typedef __attribute__((ext_vector_type(4))) float f32x4;

__device__ inline unsigned short f2bf(float f) {
    union { float f; unsigned u; } v; v.f = f;
    unsigned r = v.u + 0x7FFF + ((v.u >> 16) & 1);   // RNE
    return (unsigned short)(r >> 16);
}
__device__ inline float bf2f(unsigned short b) {
    union { unsigned u; float f; } v; v.u = ((unsigned)b) << 16;
    return v.f;
}

// async 16B global->LDS (R14: took gemm 48->~26us)
#define GLOAD_LDS16(g, l)                                                  \
    __builtin_amdgcn_global_load_lds(                                      \
        (const __attribute__((address_space(1))) unsigned int*)(g),        \
        (__attribute__((address_space(3))) unsigned int*)(l), 16, 0, 0)

// ---------------------------------------------------------------------------
// k_init: W1/W2 fp32->bf16 cvt + part zero + deg=1 + done zero, one dispatch.
// ---------------------------------------------------------------------------
__global__ void k_init(const float* __restrict__ W1, const float* __restrict__ W2,
                       unsigned short* __restrict__ W1b, unsigned short* __restrict__ W2b,
                       float* __restrict__ part, int* __restrict__ deg,
                       int* __restrict__ done) {
    int i = blockIdx.x * 256 + threadIdx.x;   // grid 512*256 = 131072
    const float* src = (i < 65536) ? W1 : W2;
    unsigned short* dst = (i < 65536) ? W1b : W2b;
    int j = i & 65535;
    float4 v = ((const float4*)src)[j];
    ushort4 o;
    o.x = f2bf(v.x); o.y = f2bf(v.y); o.z = f2bf(v.z); o.w = f2bf(v.w);
    ((ushort4*)dst)[j] = o;
    if (i < 2 * M_SEL) part[i] = 0.f;
    if (i < N_NODES) deg[i] = 1;              // self-loop base for histogram
    if (i < 128) done[i] = 0;                 // gemm<1> panel counters
}

// ---------------------------------------------------------------------------
// Fused transform + hist. Blocks 0..1562: h = x@W.T (bf16) + a_src/a_dst.
// Blocks 1563..3125: degree histogram (deg pre-initialized by k_init).
// ---------------------------------------------------------------------------
#define TR_NPW 8
#define TR_BLKS 1563

__global__ __launch_bounds__(256) void k_transform_hist(
        const float* __restrict__ x, const float* __restrict__ W,
        const float* __restrict__ att_src, const float* __restrict__ att_dst,
        unsigned short* __restrict__ h, float* __restrict__ a_src,
        float* __restrict__ a_dst, const int* __restrict__ ei,
        int* __restrict__ deg) {
    if (blockIdx.x >= TR_BLKS) {
        int e = (blockIdx.x - TR_BLKS) * 256 + threadIdx.x;
        if (e < N_EDGES) atomicAdd(&deg[ei[N_EDGES + e]], 1);
        return;
    }
    int wave = threadIdx.x >> 6, lane = threadIdx.x & 63;
    int c0 = lane * 8;

    float wreg[40];
    const float4* wp = (const float4*)(W + c0 * IN_DIM);
#pragma unroll
    for (int i = 0; i < 10; i++) ((float4*)wreg)[i] = wp[i];
    float sas[8], sad[8];
    *(float4*)&sas[0] = *(const float4*)(att_src + c0);
    *(float4*)&sas[4] = *(const float4*)(att_src + c0 + 4);
    *(float4*)&sad[0] = *(const float4*)(att_dst + c0);
    *(float4*)&sad[4] = *(const float4*)(att_dst + c0 + 4);

    int n0 = (blockIdx.x * 4 + wave) * TR_NPW;
#pragma unroll
    for (int t = 0; t < TR_NPW; t++) {
        int n = n0 + t;
        if (n >= N_NODES) return;
        float xv[IN_DIM];
#pragma unroll
        for (int i = 0; i < IN_DIM; i++) xv[i] = x[n * IN_DIM + i];

        float ps = 0.f, pd = 0.f;
        bf16x8 hv8;
#pragma unroll
        for (int j = 0; j < 8; j++) {
            float acc = 0.f;
#pragma unroll
            for (int i = 0; i < IN_DIM; i++) acc += xv[i] * wreg[j * IN_DIM + i];
            hv8[j] = (short)f2bf(acc);
            ps += acc * sas[j];
            pd += acc * sad[j];
        }
        *(bf16x8*)(h + (size_t)n * HC + c0) = hv8;

#pragma unroll
        for (int off = 8; off >= 1; off >>= 1) {
            ps += __shfl_xor(ps, off);
            pd += __shfl_xor(pd, off);
        }
        if ((lane & 15) == 0) {
            int head = lane >> 4;
            a_src[n * HEADS + head] = ps;
            a_dst[n * HEADS + head] = pd;
        }
    }
}

// ---------------------------------------------------------------------------
// CSR build (multi-block; R4 lesson: never single-block the scan)
// ---------------------------------------------------------------------------
#define NSCAN_BLK 196

__global__ void k_scan1(const int* __restrict__ deg, int* __restrict__ excl,
                        int* __restrict__ bsum) {
    __shared__ int s[256];
    int i = blockIdx.x * 256 + threadIdx.x;
    int v = (i < N_NODES) ? deg[i] : 0;
    s[threadIdx.x] = v;
    __syncthreads();
    for (int off = 1; off < 256; off <<= 1) {
        int t = (threadIdx.x >= off) ? s[threadIdx.x - off] : 0;
        __syncthreads();
        s[threadIdx.x] += t;
        __syncthreads();
    }
    if (i < N_NODES) excl[i] = s[threadIdx.x] - v;
    if (threadIdx.x == 255) bsum[blockIdx.x] = s[255];
}

__global__ void k_scan3fill(const int* __restrict__ excl, const int* __restrict__ bsum,
                            int* __restrict__ offs, int* __restrict__ curs,
                            int* __restrict__ csr) {
    __shared__ int part[256];
    int tid = threadIdx.x;
    part[tid] = (tid < NSCAN_BLK) ? bsum[tid] : 0;
    __syncthreads();
    for (int off = 1; off < 256; off <<= 1) {
        int t = (tid >= off) ? part[tid - off] : 0;
        __syncthreads();
        part[tid] += t;
        __syncthreads();
    }
    int blockoff = (blockIdx.x == 0) ? 0 : part[blockIdx.x - 1];
    int i = blockIdx.x * 256 + tid;
    if (i < N_NODES) {
        int o = excl[i] + blockoff;
        offs[i] = o;
        csr[o] = i;          // self loop in slot 0
        curs[i] = o + 1;
    }
}

__global__ void k_fill_edges(const int* __restrict__ ei, int* __restrict__ cursor,
                             int* __restrict__ csr) {
    int e = blockIdx.x * 256 + threadIdx.x;
    if (e < N_EDGES) {
        int d = ei[N_EDGES + e];
        int pos = atomicAdd(&cursor[d], 1);
        csr[pos] = ei[e];
    }
}

// ---------------------------------------------------------------------------
// Aggregate — R5/R18 body (best measured: 46.5us). 8 structural variants
// (R6-R20: sched_barrier, branch-free, asm batch, LDS-DMA, launch-bounds,
// 1024-thread blocks, recompute) all >= this. Random-gather concurrency is
// capped by per-CU outstanding misses — structural floor.
// ---------------------------------------------------------------------------
__global__ void k_aggregate(const unsigned short* __restrict__ h, const float* __restrict__ a_src,
                            const float* __restrict__ a_dst, const int* __restrict__ csr,
                            const int* __restrict__ offs, const int* __restrict__ deg,
                            const float* __restrict__ bias, unsigned short* __restrict__ emb_sel) {
    int wave = threadIdx.x >> 6, lane = threadIdx.x & 63;
    int w = blockIdx.x * 4 + wave;
    if (w >= M_SEL) return;
    int n = ((w >> 2) << 3) + (w & 3);   // TEAM_IDX[w]

    int base = offs[n];
    int dn = deg[n];
    int head = lane >> 4, egrp = lane & 15;
    int c0 = lane * 8;

    float acc[8];
#pragma unroll
    for (int j = 0; j < 8; j++) acc[j] = -INFINITY;

    if (dn <= 16) {
        int s_e = 0;
        float t = -INFINITY;
        if (egrp < dn) {
            s_e = csr[base + egrp];
            t = a_src[s_e * HEADS + head] + a_dst[n * HEADS + head];
            t = (t > 0.f) ? t : NEG_SLOPE * t;
        }
        float m = t;
#pragma unroll
        for (int off = 8; off >= 1; off >>= 1) m = fmaxf(m, __shfl_xor(m, off));
        float ex = (egrp < dn) ? __expf(t - m) : 0.f;
        float den = ex;
#pragma unroll
        for (int off = 8; off >= 1; off >>= 1) den += __shfl_xor(den, off);
        float attn = ex / den;   // this lane's edge attn (for its head)

        int e = 0;
        for (; e + 4 <= dn; e += 4) {
            int s0 = __shfl(s_e, e + 0), s1 = __shfl(s_e, e + 1);
            int s2 = __shfl(s_e, e + 2), s3 = __shfl(s_e, e + 3);
            float a0 = __shfl(attn, (head << 4) | (e + 0));
            float a1 = __shfl(attn, (head << 4) | (e + 1));
            float a2 = __shfl(attn, (head << 4) | (e + 2));
            float a3 = __shfl(attn, (head << 4) | (e + 3));
            bf16x8 v0 = *(const bf16x8*)(h + (size_t)s0 * HC + c0);
            bf16x8 v1 = *(const bf16x8*)(h + (size_t)s1 * HC + c0);
            bf16x8 v2 = *(const bf16x8*)(h + (size_t)s2 * HC + c0);
            bf16x8 v3 = *(const bf16x8*)(h + (size_t)s3 * HC + c0);
#pragma unroll
            for (int j = 0; j < 8; j++) {
                acc[j] = fmaxf(acc[j], bf2f((unsigned short)v0[j]) * a0);
                acc[j] = fmaxf(acc[j], bf2f((unsigned short)v1[j]) * a1);
                acc[j] = fmaxf(acc[j], bf2f((unsigned short)v2[j]) * a2);
                acc[j] = fmaxf(acc[j], bf2f((unsigned short)v3[j]) * a3);
            }
        }
        for (; e < dn; e++) {
            int s = __shfl(s_e, e);
            float a = __shfl(attn, (head << 4) | e);
            bf16x8 v = *(const bf16x8*)(h + (size_t)s * HC + c0);
#pragma unroll
            for (int j = 0; j < 8; j++)
                acc[j] = fmaxf(acc[j], bf2f((unsigned short)v[j]) * a);
        }
    } else {
        // fallback: 3-pass (rare, dn>16)
        float adn = a_dst[n * HEADS + head];
        float m = -INFINITY;
        for (int e0 = 0; e0 < dn; e0 += 16) {
            int e = e0 + egrp;
            if (e < dn) {
                int s = csr[base + e];
                float t = a_src[s * HEADS + head] + adn;
                t = (t > 0.f) ? t : NEG_SLOPE * t;
                m = fmaxf(m, t);
            }
        }
#pragma unroll
        for (int off = 8; off >= 1; off >>= 1) m = fmaxf(m, __shfl_xor(m, off));
        float den = 0.f;
        for (int e0 = 0; e0 < dn; e0 += 16) {
            int e = e0 + egrp;
            if (e < dn) {
                int s = csr[base + e];
                float t = a_src[s * HEADS + head] + adn;
                t = (t > 0.f) ? t : NEG_SLOPE * t;
                den += __expf(t - m);
            }
        }
#pragma unroll
        for (int off = 8; off >= 1; off >>= 1) den += __shfl_xor(den, off);
        float invden = 1.0f / den;
        for (int e = 0; e < dn; e++) {
            int s = csr[base + e];
            float t = a_src[s * HEADS + head] + adn;
            t = (t > 0.f) ? t : NEG_SLOPE * t;
            float attn = __expf(t - m) * invden;
            bf16x8 hv = *(const bf16x8*)(h + (size_t)s * HC + c0);
#pragma unroll
            for (int j = 0; j < 8; j++)
                acc[j] = fmaxf(acc[j], bf2f((unsigned short)hv[j]) * attn);
        }
    }

    bf16x8 ov;
#pragma unroll
    for (int j = 0; j < 8; j++) ov[j] = (short)f2bf(acc[j] + bias[c0 + j]);
    *(bf16x8*)(emb_sel + (size_t)w * HC + c0) = ov;
}

// ---------------------------------------------------------------------------
// GEMM (R18 structure + XCD-affinity + fused tanh), unchanged from R19.
// BM=256 x BN=128, BK=64, 256 threads (4 m-waves), global_load_lds staging.
// 1D grid 416: xcd=bid&7, q=bid>>3, p = xcd + 8*(q>>2), x = q&3 — a panel's
// 4 x-blocks land on ONE XCD => A-panel L2-served.
// MODE 0: store relu bf16. MODE 1: fused final layer + per-panel tanh.
// ---------------------------------------------------------------------------
template <int MODE>
__global__ __launch_bounds__(256, 2) void k_gemm(const unsigned short* __restrict__ A, int M,
                                                 const unsigned short* __restrict__ Wt,
                                                 const float* __restrict__ bias,
                                                 unsigned short* __restrict__ C,
                                                 const float* __restrict__ W3,
                                                 float* __restrict__ part,
                                                 int* __restrict__ done,
                                                 const float* __restrict__ b3,
                                                 float* __restrict__ outp) {
    __shared__ unsigned short As[256 * 64];   // 32KB
    __shared__ unsigned short Bs[128 * 64];   // 16KB
    int tid = threadIdx.x;
    int bid = blockIdx.x;
    int xcd = bid & 7, q = bid >> 3;
    int p = xcd + 8 * (q >> 2);               // m-panel 0..97 (+ holes)
    int xb = q & 3;                           // n-block 0..3
    if (p >= 98) return;
    int m0 = p * 256;
    int o0 = xb * 128;
    int wv = tid >> 6, lane = tid & 63;       // wave = m-stripe

    f32x4 acc[4][8];
#pragma unroll
    for (int i = 0; i < 4; i++)
#pragma unroll
        for (int j = 0; j < 8; j++) acc[i][j] = (f32x4){0.f, 0.f, 0.f, 0.f};

    for (int k0 = 0; k0 < HC; k0 += 64) {
#pragma unroll
        for (int c = 0; c < 8; c++) {         // A: 256x64 = 32KB
            int off = c * 4096 + tid * 16;
            int row = off >> 7, col = (off & 127) >> 1;
            GLOAD_LDS16(A + (size_t)(m0 + row) * HC + k0 + col, (char*)As + off);
        }
#pragma unroll
        for (int c = 0; c < 4; c++) {         // B: 128x64 = 16KB
            int off = c * 4096 + tid * 16;
            int row = off >> 7, col = (off & 127) >> 1;
            GLOAD_LDS16(Wt + (size_t)(o0 + row) * HC + k0 + col, (char*)Bs + off);
        }
        __syncthreads();   // drains vmcnt: staged data visible

#pragma unroll
        for (int kk = 0; kk < 2; kk++) {
            int kb = kk * 32 + (lane >> 4) * 8;
            bf16x8 af[4], bfr[8];
#pragma unroll
            for (int mi = 0; mi < 4; mi++)
                af[mi] = *(const bf16x8*)(&As[(wv * 64 + mi * 16 + (lane & 15)) * 64 + kb]);
#pragma unroll
            for (int ni = 0; ni < 8; ni++)
                bfr[ni] = *(const bf16x8*)(&Bs[(ni * 16 + (lane & 15)) * 64 + kb]);
#pragma unroll
            for (int mi = 0; mi < 4; mi++)
#pragma unroll
                for (int ni = 0; ni < 8; ni++)
                    acc[mi][ni] = __builtin_amdgcn_mfma_f32_16x16x32_bf16(
                        af[mi], bfr[ni], acc[mi][ni], 0, 0, 0);
        }
        __syncthreads();   // before next stage overwrites the buffer
    }

    if (MODE == 0) {
#pragma unroll
        for (int ni = 0; ni < 8; ni++) {
            int ncol = o0 + ni * 16 + (lane & 15);
            float bv = bias[ncol];
#pragma unroll
            for (int mi = 0; mi < 4; mi++) {
                int mbase = m0 + wv * 64 + mi * 16 + (lane >> 4) * 4;
#pragma unroll
                for (int r = 0; r < 4; r++) {
                    int m = mbase + r;
                    if (m < M) {
                        float v = fmaxf(acc[mi][ni][r] + bv, 0.f);
                        C[(size_t)m * HC + ncol] = f2bf(v);
                    }
                }
            }
        }
    } else {
        float p0[4][4], p1[4][4];
#pragma unroll
        for (int mi = 0; mi < 4; mi++)
#pragma unroll
            for (int r = 0; r < 4; r++) { p0[mi][r] = 0.f; p1[mi][r] = 0.f; }
#pragma unroll
        for (int ni = 0; ni < 8; ni++) {
            int ncol = o0 + ni * 16 + (lane & 15);
            float bv = bias[ncol];
            float w0 = W3[ncol], w1 = W3[HC + ncol];
#pragma unroll
            for (int mi = 0; mi < 4; mi++)
#pragma unroll
                for (int r = 0; r < 4; r++) {
                    float v = fmaxf(acc[mi][ni][r] + bv, 0.f);
                    p0[mi][r] += v * w0;
                    p1[mi][r] += v * w1;
                }
        }
#pragma unroll
        for (int mi = 0; mi < 4; mi++)
#pragma unroll
            for (int r = 0; r < 4; r++) {
                float a0 = p0[mi][r], a1 = p1[mi][r];
#pragma unroll
                for (int off = 8; off >= 1; off >>= 1) {
                    a0 += __shfl_xor(a0, off);
                    a1 += __shfl_xor(a1, off);
                }
                int m = m0 + wv * 64 + mi * 16 + (lane >> 4) * 4 + r;
                if ((lane & 15) == 0 && m < M) {
                    atomicAdd(&part[m * 2 + 0], a0);
                    atomicAdd(&part[m * 2 + 1], a1);
                }
            }

        // completion: last of the panel's 4 blocks applies tanh (fused k_tanh)
        __syncthreads();
        __shared__ int lastf;
        if (tid == 0) {
            __threadfence();
            int old = atomicAdd(&done[p], 1);
            lastf = (old == 3);
        }
        __syncthreads();
        if (lastf) {
            for (int i = tid; i < 512; i += 256) {
                int idx = p * 512 + i;
                if (idx < 2 * M_SEL) {
                    float v = __hip_atomic_load(&part[idx], __ATOMIC_RELAXED,
                                                __HIP_MEMORY_SCOPE_AGENT);
                    outp[idx] = tanhf(v + b3[i & 1]);
                }
            }
        }
    }
}

// ---------------------------------------------------------------------------
extern "C" void kernel_launch(void* const* d_in, const int* in_sizes, int n_in,
                              void* d_out, int out_size, void* d_ws, size_t ws_size,
                              hipStream_t stream) {
    const float* x       = (const float*)d_in[0];
    const int*   ei      = (const int*)d_in[1];
    const float* W       = (const float*)d_in[3];
    const float* att_src = (const float*)d_in[4];
    const float* att_dst = (const float*)d_in[5];
    const float* bias    = (const float*)d_in[6];
    const float* W1      = (const float*)d_in[7];
    const float* b1      = (const float*)d_in[8];
    const float* W2      = (const float*)d_in[9];
    const float* b2      = (const float*)d_in[10];
    const float* W3      = (const float*)d_in[11];
    const float* b3      = (const float*)d_in[12];
    float* out = (float*)d_out;

    char* ws = (char*)d_ws;
    unsigned short* h       = (unsigned short*)(ws);               // 51,200,000
    unsigned short* emb_sel = (unsigned short*)(ws + 51200000);    // 25,600,000
    unsigned short* h1      = (unsigned short*)(ws + 76800000);    // 25,600,000
    float* part  = (float*)(ws + 102400000);                       //    200,000 (also OOB-read slack)
    float* a_src = (float*)(ws + 102600000);                       //    800,000
    float* a_dst = (float*)(ws + 103400000);                       //    800,000
    int*   deg   = (int*)  (ws + 104200000);                       //    200,000
    int*   offs  = (int*)  (ws + 104400000);                       //    200,000
    int*   curs  = (int*)  (ws + 104600000);                       //    200,000
    int*   excl  = (int*)  (ws + 104800000);                       //    200,000
    int*   bsum  = (int*)  (ws + 105000000);                       //      1,024
    int*   done  = (int*)  (ws + 105001024);                       //        512
    int*   csr   = (int*)  (ws + 105001536);                       //  1,800,000
    unsigned short* W1b = (unsigned short*)(ws + 106801536);       //    524,288
    unsigned short* W2b = (unsigned short*)(ws + 107325824);       //    524,288  (~108 MB)

    k_init<<<512, 256, 0, stream>>>(W1, W2, W1b, W2b, part, deg, done);
    k_transform_hist<<<TR_BLKS * 2, 256, 0, stream>>>(x, W, att_src, att_dst, h,
                                                      a_src, a_dst, ei, deg);
    k_scan1<<<NSCAN_BLK, 256, 0, stream>>>(deg, excl, bsum);
    k_scan3fill<<<NSCAN_BLK, 256, 0, stream>>>(excl, bsum, offs, curs, csr);
    k_fill_edges<<<(N_EDGES + 255) / 256, 256, 0, stream>>>(ei, curs, csr);
    k_aggregate<<<6250, 256, 0, stream>>>(h, a_src, a_dst, csr, offs, deg, bias, emb_sel);

    k_gemm<0><<<416, 256, 0, stream>>>(emb_sel, M_SEL, W1b, b1, h1, nullptr, nullptr,
                                       nullptr, nullptr, nullptr);
    k_gemm<1><<<416, 256, 0, stream>>>(h1, M_SEL, W2b, b2, nullptr, W3, part,
                                       done, b3, out);
}